// Round 8
// baseline (770.425 us; speedup 1.0000x reference)
//
#include <hip/hip_runtime.h>

// Round 8: cut the scan's per-CU line-fetch count (the real bottleneck).
//   R4/R5/R6/R7 all hit ~13 cyc/entry: per-CU line-fetch throughput
//   (~MSHR/L3-latency ~0.09 lines/cyc) on ~64K lines/block. Fix: sort by
//   (dest_chunk 4096, src_chunk 4096) = 2401 buckets; scan block owns
//   (dest, group-of-10 src windows), stages each 64 KB window in LDS once.
//   Lines/CU: 10K staging + 8K entries ~= 18K (was 64K).
//   Sort = R6's zero-global-atomic radix, col_scan fixed (8-way unroll).
// Entry = (src_local(12b) | dest_local(12b)<<12, w=0.5/d).

#define CA_BITS 12
#define CHUNK 4096
#define NCHUNK 49                 // ceil(200000/4096)
#define NB (NCHUNK * NCHUNK)      // 2401
#define PPB 16384
#define CS_BLOCK 1024
#define SCAN_BLOCK 1024
#define NGRP 5                    // src-window groups per dest chunk
#define GRP_W 10                  // windows per group (last group has 9)

// ---------- Pass 1: per-block bucket histogram (no global atomics) ----------
__global__ __launch_bounds__(CS_BLOCK) void count_pairs(
    const int2* __restrict__ idx, unsigned* __restrict__ counts2d, int npairs)
{
    __shared__ unsigned hist[NB];
    for (int b = threadIdx.x; b < NB; b += CS_BLOCK) hist[b] = 0;
    __syncthreads();
    const int p0 = blockIdx.x * PPB, p1 = min(p0 + PPB, npairs);
    for (int p = p0 + threadIdx.x; p < p1; p += CS_BLOCK) {
        int2 ij = idx[p];
        unsigned ci = (unsigned)ij.x >> CA_BITS;
        unsigned cj = (unsigned)ij.y >> CA_BITS;
        atomicAdd(&hist[ci * NCHUNK + cj], 1u);
        atomicAdd(&hist[cj * NCHUNK + ci], 1u);
    }
    __syncthreads();
    unsigned* row = counts2d + (size_t)blockIdx.x * NB;
    for (int b = threadIdx.x; b < NB; b += CS_BLOCK) row[b] = hist[b];
}

// ---------- Pass 2a: column scan over blocks (8-way unrolled: MLP fix) ------
__global__ __launch_bounds__(256) void col_scan(
    const unsigned* __restrict__ counts2d, unsigned* __restrict__ base2d,
    unsigned* __restrict__ totals, int nblk)
{
    int b = blockIdx.x * 256 + threadIdx.x;
    if (b >= NB) return;
    unsigned run = 0;
    int k = 0;
    for (; k + 8 <= nblk; k += 8) {
        unsigned v[8];
#pragma unroll
        for (int u = 0; u < 8; ++u) v[u] = counts2d[(size_t)(k + u) * NB + b];
#pragma unroll
        for (int u = 0; u < 8; ++u) {
            base2d[(size_t)(k + u) * NB + b] = run;
            run += v[u];
        }
    }
    for (; k < nblk; ++k) {
        unsigned v = counts2d[(size_t)k * NB + b];
        base2d[(size_t)k * NB + b] = run;
        run += v;
    }
    totals[b] = run;
}

// ---------- Pass 2b: exclusive scan of 2401 totals -> offsets ----------
__global__ __launch_bounds__(1024) void scan_offsets(
    const unsigned* __restrict__ totals, unsigned* __restrict__ offsets)
{
    __shared__ unsigned ts[1024];
    const int t = threadIdx.x;
    unsigned v[3], sum = 0;
#pragma unroll
    for (int q = 0; q < 3; ++q) {
        int b = t * 3 + q;
        v[q] = (b < NB) ? totals[b] : 0u;
        sum += v[q];
    }
    ts[t] = sum;
    __syncthreads();
    for (int d = 1; d < 1024; d <<= 1) {
        unsigned o = (t >= d) ? ts[t - d] : 0u;
        __syncthreads();
        ts[t] += o;
        __syncthreads();
    }
    unsigned ex = ts[t] - sum;
#pragma unroll
    for (int q = 0; q < 3; ++q) {
        int b = t * 3 + q;
        if (b < NB) offsets[b] = ex;
        ex += v[q];
    }
    if (t == 1023) offsets[NB] = ts[1023];
}

// ---------- Pass 3: scatter entries to exact positions ----------
__global__ __launch_bounds__(CS_BLOCK) void scatter_pairs(
    const int2* __restrict__ idx, const float* __restrict__ dist,
    uint2* __restrict__ entries, const unsigned* __restrict__ offsets,
    const unsigned* __restrict__ base2d, int npairs)
{
    __shared__ unsigned rankh[NB];
    __shared__ unsigned baseL[NB];
    const unsigned* brow = base2d + (size_t)blockIdx.x * NB;
    for (int b = threadIdx.x; b < NB; b += CS_BLOCK) {
        rankh[b] = 0u;
        baseL[b] = offsets[b] + brow[b];
    }
    __syncthreads();
    const int p0 = blockIdx.x * PPB, p1 = min(p0 + PPB, npairs);
    for (int p = p0 + threadIdx.x; p < p1; p += CS_BLOCK) {
        int2 ij = idx[p];
        float w = 0.5f / dist[p];
        unsigned ai = (unsigned)ij.x, aj = (unsigned)ij.y;
        unsigned ci = ai >> CA_BITS, cj = aj >> CA_BITS;
        unsigned b0 = ci * NCHUNK + cj, b1 = cj * NCHUNK + ci;
        unsigned wb = __float_as_uint(w);
        unsigned li = ai & (CHUNK - 1), lj = aj & (CHUNK - 1);
        unsigned r0 = atomicAdd(&rankh[b0], 1u);
        entries[baseL[b0] + r0] = make_uint2(lj | (li << 12), wb);   // dest i, src j
        unsigned r1 = atomicAdd(&rankh[b1], 1u);
        entries[baseL[b1] + r1] = make_uint2(li | (lj << 12), wb);   // dest j, src i
    }
}

// ---------- Pass 4: windowed scan — stage only OUR src windows ----------
__global__ __launch_bounds__(SCAN_BLOCK) void scan_win(
    const float4* __restrict__ charges, const uint2* __restrict__ entries,
    const unsigned* __restrict__ offsets, float* __restrict__ slabs, int natoms)
{
    extern __shared__ float lds[];   // [0,4*CHUNK): acc ch-major; [4*CHUNK,8*CHUNK): staged window
    const int c = blockIdx.x / NGRP;
    const int g = blockIdx.x - c * NGRP;
    for (int e = threadIdx.x; e < 4 * CHUNK; e += SCAN_BLOCK) lds[e] = 0.f;

    const int s0 = g * GRP_W;
    const int s1 = min(s0 + GRP_W, NCHUNK);
    float* stg = lds + 4 * CHUNK;

    for (int s = s0; s < s1; ++s) {
        __syncthreads();                       // prior window's reads done (covers zero-init too)
        const int a0 = s << CA_BITS;
        for (int a = threadIdx.x; a < CHUNK; a += SCAN_BLOCK) {
            float4 q = (a0 + a < natoms) ? charges[a0 + a] : make_float4(0.f, 0.f, 0.f, 0.f);
            stg[a]             = q.x;
            stg[CHUNK + a]     = q.y;
            stg[2 * CHUNK + a] = q.z;
            stg[3 * CHUNK + a] = q.w;
        }
        __syncthreads();
        const unsigned r0 = offsets[c * NCHUNK + s];
        const unsigned r1 = offsets[c * NCHUNK + s + 1];
        unsigned e = r0 + threadIdx.x;
        for (; e + 3u * SCAN_BLOCK < r1; e += 4u * SCAN_BLOCK) {
            uint2 en[4];
#pragma unroll
            for (int u = 0; u < 4; ++u) en[u] = entries[e + u * SCAN_BLOCK];
#pragma unroll
            for (int u = 0; u < 4; ++u) {
                float w = __uint_as_float(en[u].y);
                unsigned sl = en[u].x & (CHUNK - 1);
                unsigned dl = (en[u].x >> 12) & (CHUNK - 1);
                atomicAdd(&lds[dl],             stg[sl] * w);
                atomicAdd(&lds[CHUNK + dl],     stg[CHUNK + sl] * w);
                atomicAdd(&lds[2 * CHUNK + dl], stg[2 * CHUNK + sl] * w);
                atomicAdd(&lds[3 * CHUNK + dl], stg[3 * CHUNK + sl] * w);
            }
        }
        for (; e < r1; e += SCAN_BLOCK) {
            uint2 en = entries[e];
            float w = __uint_as_float(en.y);
            unsigned sl = en.x & (CHUNK - 1);
            unsigned dl = (en.x >> 12) & (CHUNK - 1);
            atomicAdd(&lds[dl],             stg[sl] * w);
            atomicAdd(&lds[CHUNK + dl],     stg[CHUNK + sl] * w);
            atomicAdd(&lds[2 * CHUNK + dl], stg[2 * CHUNK + sl] * w);
            atomicAdd(&lds[3 * CHUNK + dl], stg[3 * CHUNK + sl] * w);
        }
    }
    __syncthreads();

    const int c0 = c << CA_BITS;
    const int nv = min(CHUNK, natoms - c0);
    float4* dst = (float4*)(slabs + (size_t)blockIdx.x * (4 * CHUNK));
    for (int a = threadIdx.x; a < nv; a += SCAN_BLOCK)
        dst[a] = make_float4(lds[a], lds[CHUNK + a], lds[2 * CHUNK + a], lds[3 * CHUNK + a]);
}

// ---------- reduce NGRP slabs per dest chunk ----------
__global__ __launch_bounds__(256) void win_reduce(
    const float4* __restrict__ slabs, float4* __restrict__ out, int natoms)
{
    int a = blockIdx.x * 256 + threadIdx.x;
    if (a >= natoms) return;
    int c = a >> CA_BITS, l = a & (CHUNK - 1);
    const float4* p = slabs + ((size_t)c * NGRP) * CHUNK + l;
    float4 acc = make_float4(0.f, 0.f, 0.f, 0.f);
#pragma unroll
    for (int g = 0; g < NGRP; ++g) {
        float4 v = p[(size_t)g * CHUNK];
        acc.x += v.x; acc.y += v.y; acc.z += v.z; acc.w += v.w;
    }
    out[a] = acc;
}

// ---------- Fallback (R3): redundant chunk scan ----------
#define FB_BLOCK 1024
#define FB_NSL 10
#define FB_UNROLL 8
template<int CHUNK_ATOMS, bool USE_WS>
__global__ __launch_bounds__(FB_BLOCK) void chunk_scan(
    const float4* __restrict__ charges, const int2* __restrict__ idx,
    const float* __restrict__ dist, float* __restrict__ dest,
    int npairs, int natoms)
{
    constexpr int CH_ELEMS = CHUNK_ATOMS * 4;
    extern __shared__ float sm[];
    const int c  = blockIdx.x / FB_NSL;
    const int s  = blockIdx.x - c * FB_NSL;
    const int c0 = c * CHUNK_ATOMS;
    const int cn = min(CHUNK_ATOMS, natoms - c0);
    for (int e = threadIdx.x; e < CH_ELEMS; e += FB_BLOCK) sm[e] = 0.f;
    __syncthreads();
    const int p0 = (int)((long long)npairs * s       / FB_NSL);
    const int p1 = (int)((long long)npairs * (s + 1) / FB_NSL);
    const int nbatch = (p1 - p0) / (FB_BLOCK * FB_UNROLL);
    int p = p0 + threadIdx.x;
    for (int b = 0; b < nbatch; ++b, p += FB_BLOCK * FB_UNROLL) {
        int2 ij[FB_UNROLL]; float dd[FB_UNROLL];
#pragma unroll
        for (int u = 0; u < FB_UNROLL; ++u) { ij[u] = idx[p + u * FB_BLOCK]; dd[u] = dist[p + u * FB_BLOCK]; }
#pragma unroll
        for (int u = 0; u < FB_UNROLL; ++u) {
            unsigned li = (unsigned)(ij[u].x - c0), lj = (unsigned)(ij[u].y - c0);
            float w = 0.5f / dd[u];
            if (li < (unsigned)cn) {
                float4 cq = charges[ij[u].y]; float* bp = sm + li * 4;
                atomicAdd(bp + 0, cq.x * w); atomicAdd(bp + 1, cq.y * w);
                atomicAdd(bp + 2, cq.z * w); atomicAdd(bp + 3, cq.w * w);
            }
            if (lj < (unsigned)cn) {
                float4 cq = charges[ij[u].x]; float* bp = sm + lj * 4;
                atomicAdd(bp + 0, cq.x * w); atomicAdd(bp + 1, cq.y * w);
                atomicAdd(bp + 2, cq.z * w); atomicAdd(bp + 3, cq.w * w);
            }
        }
    }
    for (; p < p1; p += FB_BLOCK) {
        int2 ij = idx[p];
        unsigned li = (unsigned)(ij.x - c0), lj = (unsigned)(ij.y - c0);
        if (li < (unsigned)cn || lj < (unsigned)cn) {
            float w = 0.5f / dist[p];
            if (li < (unsigned)cn) {
                float4 cq = charges[ij.y]; float* bp = sm + li * 4;
                atomicAdd(bp + 0, cq.x * w); atomicAdd(bp + 1, cq.y * w);
                atomicAdd(bp + 2, cq.z * w); atomicAdd(bp + 3, cq.w * w);
            }
            if (lj < (unsigned)cn) {
                float4 cq = charges[ij.x]; float* bp = sm + lj * 4;
                atomicAdd(bp + 0, cq.x * w); atomicAdd(bp + 1, cq.y * w);
                atomicAdd(bp + 2, cq.z * w); atomicAdd(bp + 3, cq.w * w);
            }
        }
    }
    __syncthreads();
    const int nvalid = cn * 4;
    if (USE_WS) {
        float* dst = dest + (size_t)blockIdx.x * CH_ELEMS;
        for (int e = threadIdx.x; e < nvalid; e += FB_BLOCK) dst[e] = sm[e];
    } else {
        float* dst = dest + (size_t)c0 * 4;
        for (int e = threadIdx.x; e < nvalid; e += FB_BLOCK) atomicAdd(dst + e, sm[e]);
    }
}

template<int CH_ELEMS, int NS>
__global__ __launch_bounds__(256) void chunk_reduce(
    const float* __restrict__ ws, float* __restrict__ out, int total)
{
    int g = blockIdx.x * blockDim.x + threadIdx.x;
    if (g >= total) return;
    int c = g / CH_ELEMS;
    int local = g - c * CH_ELEMS;
    const float* p = ws + ((size_t)c * NS) * CH_ELEMS + local;
    float acc = 0.f;
#pragma unroll
    for (int s = 0; s < NS; ++s) acc += p[(size_t)s * CH_ELEMS];
    out[g] = acc;
}

extern "C" void kernel_launch(void* const* d_in, const int* in_sizes, int n_in,
                              void* d_out, int out_size, void* d_ws, size_t ws_size,
                              hipStream_t stream) {
    const float4* charges = (const float4*)d_in[0];
    const int2*   idx     = (const int2*)  d_in[1];
    const float*  dist    = (const float*) d_in[2];
    float*        out     = (float*)d_out;

    const int natoms = in_sizes[0] / 4;     // 200000
    const int npairs = in_sizes[2];         // 8000000
    const int total  = out_size;            // 800000

    int dev = 0;
    hipGetDevice(&dev);
    int maxShm = 0;
    hipDeviceGetAttribute(&maxShm, hipDeviceAttributeMaxSharedMemoryPerBlock, dev);
    const bool big = (maxShm >= 131072);

    const int nblk = (npairs + PPB - 1) / PPB;      // 489

    // ws layout
    const size_t o_offsets = 0;                                  // (NB+1)*4
    const size_t o_totals  = 16384;                              // NB*4
    const size_t o_counts  = 32768;
    const size_t c2_bytes  = ((size_t)nblk * NB * 4 + 255) & ~(size_t)255;
    const size_t o_base    = o_counts + c2_bytes;
    const size_t o_entries = o_base + c2_bytes;
    const size_t ent_bytes = ((size_t)2 * npairs * 8 + 255) & ~(size_t)255;  // 128 MB
    const size_t o_slabs   = o_entries + ent_bytes;
    const size_t slab_bytes = (size_t)NCHUNK * NGRP * (4 * CHUNK) * 4;       // 16 MB
    const size_t need      = o_slabs + slab_bytes;               // ~153.5 MB

    if (big && ws_size >= need && natoms <= NCHUNK * CHUNK && (total & 3) == 0) {
        unsigned* offsets  = (unsigned*)((char*)d_ws + o_offsets);
        unsigned* totals   = (unsigned*)((char*)d_ws + o_totals);
        unsigned* counts2d = (unsigned*)((char*)d_ws + o_counts);
        unsigned* base2d   = (unsigned*)((char*)d_ws + o_base);
        uint2*    entries  = (uint2*)   ((char*)d_ws + o_entries);
        float*    slabs    = (float*)   ((char*)d_ws + o_slabs);

        count_pairs<<<nblk, CS_BLOCK, 0, stream>>>(idx, counts2d, npairs);
        col_scan<<<(NB + 255) / 256, 256, 0, stream>>>(counts2d, base2d, totals, nblk);
        scan_offsets<<<1, 1024, 0, stream>>>(totals, offsets);
        scatter_pairs<<<nblk, CS_BLOCK, 0, stream>>>(idx, dist, entries, offsets, base2d, npairs);
        hipFuncSetAttribute((const void*)scan_win,
                            hipFuncAttributeMaxDynamicSharedMemorySize, 8 * CHUNK * 4);
        scan_win<<<NCHUNK * NGRP, SCAN_BLOCK, 8 * CHUNK * 4, stream>>>(
            charges, entries, offsets, slabs, natoms);
        win_reduce<<<(natoms + 255) / 256, 256, 0, stream>>>(
            (const float4*)slabs, (float4*)out, natoms);
    } else if (big) {
        constexpr int CA = 8192, CE = CA * 4;
        const int C = (natoms + CA - 1) / CA;
        const int grid = C * FB_NSL;
        const size_t ws_need = (size_t)grid * CE * sizeof(float);
        if (ws_size >= ws_need) {
            hipFuncSetAttribute((const void*)chunk_scan<CA, true>,
                                hipFuncAttributeMaxDynamicSharedMemorySize, CE * 4);
            chunk_scan<CA, true><<<grid, FB_BLOCK, CE * 4, stream>>>(
                charges, idx, dist, (float*)d_ws, npairs, natoms);
            chunk_reduce<CE, FB_NSL><<<(total + 255) / 256, 256, 0, stream>>>(
                (const float*)d_ws, out, total);
        } else {
            hipMemsetAsync(d_out, 0, (size_t)total * sizeof(float), stream);
            hipFuncSetAttribute((const void*)chunk_scan<CA, false>,
                                hipFuncAttributeMaxDynamicSharedMemorySize, CE * 4);
            chunk_scan<CA, false><<<grid, FB_BLOCK, CE * 4, stream>>>(
                charges, idx, dist, out, npairs, natoms);
        }
    } else {
        constexpr int CA = 4096, CE = CA * 4;
        const int C = (natoms + CA - 1) / CA;
        const int grid = C * FB_NSL;
        const size_t ws_need = (size_t)grid * CE * sizeof(float);
        if (ws_size >= ws_need) {
            chunk_scan<CA, true><<<grid, FB_BLOCK, CE * 4, stream>>>(
                charges, idx, dist, (float*)d_ws, npairs, natoms);
            chunk_reduce<CE, FB_NSL><<<(total + 255) / 256, 256, 0, stream>>>(
                (const float*)d_ws, out, total);
        } else {
            hipMemsetAsync(d_out, 0, (size_t)total * sizeof(float), stream);
            chunk_scan<CA, false><<<grid, FB_BLOCK, CE * 4, stream>>>(
                charges, idx, dist, out, npairs, natoms);
        }
    }
}

// Round 9
// 750.704 us; speedup vs baseline: 1.0263x; 1.0263x over previous
//
#include <hip/hip_runtime.h>

// Round 9: XCD-aligned convoy scan — no sort at all.
//   R4-R8 established: scan cost == LDS fp32 atomic throughput (~3.2 cyc per
//   lane-atomic, serial per CU) -> 64M lane-atomics = ~333 us floor, invariant
//   to caching/gather/MLP. The sort (~200-390 us) buys nothing the redundant
//   R3 scan doesn't already have — R3's only extra cost was its 25x-redundant
//   pair stream served by L3 at ~3.9 TB/s. Fix the stream, delete the sort:
//   NCHUNK=32 x NSLICES=16 -> grid 512 (2 even rounds on 256 CUs);
//   s = blockIdx & 15, and blockIdx%8 XCD round-robin => every block of slice
//   s sits on XCD s%8. 16 lockstep blocks re-read the same 6 MB slice ->
//   convoy window stays in that XCD's L2. Stream hides under the atomic floor.

#define BLOCK 1024
#define NC 32            // chunks (6250 atoms, 100 KB LDS acc)
#define NSL 16           // slices; multiple of 8 for XCD alignment
#define UNROLL 8

__global__ __launch_bounds__(BLOCK) void conv_scan(
    const float4* __restrict__ charges,   // [natoms]
    const int2*   __restrict__ idx,       // [npairs]
    const float*  __restrict__ dist,      // [npairs]
    float*        __restrict__ slabs,     // [NC*NSL][ca*4]
    int npairs, int natoms, int ca)       // ca = atoms per chunk
{
    extern __shared__ float sm[];         // ca*4 floats
    const int c  = blockIdx.x >> 4;       // chunk
    const int s  = blockIdx.x & 15;       // slice -> XCD s%8
    const int c0 = c * ca;
    const int cn = min(ca, natoms - c0);

    for (int e = threadIdx.x; e < ca * 4; e += BLOCK) sm[e] = 0.f;
    __syncthreads();

    const int p0 = (int)((long long)npairs * s       / NSL);
    const int p1 = (int)((long long)npairs * (s + 1) / NSL);
    const int nbatch = (p1 - p0) / (BLOCK * UNROLL);

    int p = p0 + threadIdx.x;
    for (int b = 0; b < nbatch; ++b, p += BLOCK * UNROLL) {
        int2  ij[UNROLL];
        float dd[UNROLL];
#pragma unroll
        for (int u = 0; u < UNROLL; ++u) {
            ij[u] = idx[p + u * BLOCK];
            dd[u] = dist[p + u * BLOCK];
        }
#pragma unroll
        for (int u = 0; u < UNROLL; ++u) {
            unsigned li = (unsigned)(ij[u].x - c0);
            unsigned lj = (unsigned)(ij[u].y - c0);
            float w = 0.5f / dd[u];
            if (li < (unsigned)cn) {
                float4 cq = charges[ij[u].y];
                float* bp = sm + li * 4;
                atomicAdd(bp + 0, cq.x * w);
                atomicAdd(bp + 1, cq.y * w);
                atomicAdd(bp + 2, cq.z * w);
                atomicAdd(bp + 3, cq.w * w);
            }
            if (lj < (unsigned)cn) {
                float4 cq = charges[ij[u].x];
                float* bp = sm + lj * 4;
                atomicAdd(bp + 0, cq.x * w);
                atomicAdd(bp + 1, cq.y * w);
                atomicAdd(bp + 2, cq.z * w);
                atomicAdd(bp + 3, cq.w * w);
            }
        }
    }
    for (; p < p1; p += BLOCK) {
        int2 ij = idx[p];
        unsigned li = (unsigned)(ij.x - c0);
        unsigned lj = (unsigned)(ij.y - c0);
        if (li < (unsigned)cn || lj < (unsigned)cn) {
            float w = 0.5f / dist[p];
            if (li < (unsigned)cn) {
                float4 cq = charges[ij.y];
                float* bp = sm + li * 4;
                atomicAdd(bp + 0, cq.x * w);
                atomicAdd(bp + 1, cq.y * w);
                atomicAdd(bp + 2, cq.z * w);
                atomicAdd(bp + 3, cq.w * w);
            }
            if (lj < (unsigned)cn) {
                float4 cq = charges[ij.x];
                float* bp = sm + lj * 4;
                atomicAdd(bp + 0, cq.x * w);
                atomicAdd(bp + 1, cq.y * w);
                atomicAdd(bp + 2, cq.z * w);
                atomicAdd(bp + 3, cq.w * w);
            }
        }
    }
    __syncthreads();

    // dump accumulator slab (float4 per atom)
    float4* dst = (float4*)(slabs + (size_t)blockIdx.x * ca * 4);
    const float4* src = (const float4*)sm;
    for (int a = threadIdx.x; a < cn; a += BLOCK) dst[a] = src[a];
}

__global__ __launch_bounds__(256) void conv_reduce(
    const float4* __restrict__ slabs, float4* __restrict__ out,
    int natoms, int ca)
{
    int a = blockIdx.x * 256 + threadIdx.x;
    if (a >= natoms) return;
    int c = a / ca;
    int l = a - c * ca;
    const float4* p = slabs + ((size_t)(c * NSL)) * ca + l;
    float4 acc = make_float4(0.f, 0.f, 0.f, 0.f);
#pragma unroll
    for (int s = 0; s < NSL; ++s) {
        float4 v = p[(size_t)s * ca];
        acc.x += v.x; acc.y += v.y; acc.z += v.z; acc.w += v.w;
    }
    out[a] = acc;
}

// ---------------- fallback: direct global atomics (correct anywhere) --------
__global__ __launch_bounds__(256) void naive_scatter(
    const float4* __restrict__ charges, const int2* __restrict__ idx,
    const float* __restrict__ dist, float* __restrict__ out, int npairs)
{
    int t = blockIdx.x * blockDim.x + threadIdx.x;
    if (t >= npairs) return;
    int2  ij = idx[t];
    float w  = 0.5f / dist[t];
    float4 ci = charges[ij.x];
    float4 cj = charges[ij.y];
    float* oi = out + 4 * (size_t)ij.x;
    float* oj = out + 4 * (size_t)ij.y;
    atomicAdd(oi + 0, cj.x * w); atomicAdd(oi + 1, cj.y * w);
    atomicAdd(oi + 2, cj.z * w); atomicAdd(oi + 3, cj.w * w);
    atomicAdd(oj + 0, ci.x * w); atomicAdd(oj + 1, ci.y * w);
    atomicAdd(oj + 2, ci.z * w); atomicAdd(oj + 3, ci.w * w);
}

extern "C" void kernel_launch(void* const* d_in, const int* in_sizes, int n_in,
                              void* d_out, int out_size, void* d_ws, size_t ws_size,
                              hipStream_t stream) {
    const float4* charges = (const float4*)d_in[0];
    const int2*   idx     = (const int2*)  d_in[1];
    const float*  dist    = (const float*) d_in[2];
    float*        out     = (float*)d_out;

    const int natoms = in_sizes[0] / 4;     // 200000
    const int npairs = in_sizes[2];         // 8000000
    const int total  = out_size;            // 800000

    const int ca = (natoms + NC - 1) / NC;  // 6250
    const size_t lds_bytes  = (size_t)ca * 4 * sizeof(float);     // 100,000 B
    const size_t slab_bytes = (size_t)NC * NSL * ca * 4 * sizeof(float);  // ~51.2 MB

    int dev = 0;
    hipGetDevice(&dev);
    int maxShm = 0;
    hipDeviceGetAttribute(&maxShm, hipDeviceAttributeMaxSharedMemoryPerBlock, dev);

    if ((size_t)maxShm >= lds_bytes && ws_size >= slab_bytes && (total & 3) == 0) {
        float* slabs = (float*)d_ws;
        hipFuncSetAttribute((const void*)conv_scan,
                            hipFuncAttributeMaxDynamicSharedMemorySize, (int)lds_bytes);
        conv_scan<<<NC * NSL, BLOCK, lds_bytes, stream>>>(
            charges, idx, dist, slabs, npairs, natoms, ca);
        conv_reduce<<<(natoms + 255) / 256, 256, 0, stream>>>(
            (const float4*)slabs, (float4*)out, natoms, ca);
    } else {
        hipMemsetAsync(d_out, 0, (size_t)total * sizeof(float), stream);
        naive_scatter<<<(npairs + 255) / 256, 256, 0, stream>>>(
            charges, idx, dist, out, npairs);
    }
}

// Round 10
// 598.975 us; speedup vs baseline: 1.2862x; 1.2533x over previous
//
#include <hip/hip_runtime.h>

// Round 10: TLP probe — the one unmoved lever.
//   R4/R7/R8 sorted scans: ~13 cyc/entry, VALU ~2%, conflicts 0, HBM 4%,
//   ~90% stall. All used 1024-thr blocks + >=100KB LDS = 1 block/CU =
//   16 waves/CU. This round: chunk=2048 (32 KB acc, channel-major),
//   BLOCK=512 -> 4 blocks/CU = 32 waves/CU, grid 98x10=980.
//   Sort = R7's dest-chunk counting sort, 98 buckets.
// Entry = (src_global(18b) | dest_local(11b)<<18, w=0.5/d).

#define CA_BITS 11
#define CHUNK 2048
#define NCHUNK 98            // ceil(200000/2048)
#define NSL 10
#define SCAN_BLOCK 512
#define CT_BLOCK 256
#define SC_BLOCK 256
#define SC_PPT 8

// ---------------- Pass 0: count entries per dest chunk ----------------
__global__ __launch_bounds__(CT_BLOCK) void bucket_count(
    const int4* __restrict__ idx2, unsigned* __restrict__ counts, int npairs)
{
    __shared__ unsigned hist[NCHUNK * 4];
    for (int b = threadIdx.x; b < NCHUNK * 4; b += CT_BLOCK) hist[b] = 0;
    __syncthreads();
    const int n4 = npairs >> 1;
    const int r = threadIdx.x & 3;
    const int stride = gridDim.x * CT_BLOCK;
    for (int q = blockIdx.x * CT_BLOCK + threadIdx.x; q < n4; q += stride) {
        int4 v = idx2[q];
        atomicAdd(&hist[(((unsigned)v.x >> CA_BITS) << 2) + r], 1u);
        atomicAdd(&hist[(((unsigned)v.y >> CA_BITS) << 2) + r], 1u);
        atomicAdd(&hist[(((unsigned)v.z >> CA_BITS) << 2) + r], 1u);
        atomicAdd(&hist[(((unsigned)v.w >> CA_BITS) << 2) + r], 1u);
    }
    if ((npairs & 1) && blockIdx.x == 0 && threadIdx.x == 0) {
        const int2* idx = (const int2*)idx2;
        int2 ij = idx[npairs - 1];
        atomicAdd(&counts[(unsigned)ij.x >> CA_BITS], 1u);
        atomicAdd(&counts[(unsigned)ij.y >> CA_BITS], 1u);
    }
    __syncthreads();
    for (int b = threadIdx.x; b < NCHUNK; b += CT_BLOCK) {
        unsigned t = hist[4 * b] + hist[4 * b + 1] + hist[4 * b + 2] + hist[4 * b + 3];
        if (t) atomicAdd(&counts[b], t);
    }
}

// ---------------- prefix (98) ----------------
__global__ void bucket_prefix(const unsigned* __restrict__ counts,
                              unsigned* __restrict__ offsets,
                              unsigned* __restrict__ cursors)
{
    if (threadIdx.x == 0 && blockIdx.x == 0) {
        unsigned acc = 0;
        for (int b = 0; b < NCHUNK; ++b) {
            offsets[b] = acc; cursors[b] = acc; acc += counts[b];
        }
        offsets[NCHUNK] = acc;
    }
}

// ---------------- Pass A: scatter entries (replicated hist) ----------------
__global__ __launch_bounds__(SC_BLOCK) void bucket_scatter(
    const int2*  __restrict__ idx, const float* __restrict__ dist,
    uint2* __restrict__ entries, unsigned* __restrict__ cursors, int npairs)
{
    __shared__ unsigned hist[NCHUNK * 4];     // 392 slots
    __shared__ unsigned rbase[NCHUNK * 4];
    for (int b = threadIdx.x; b < NCHUNK * 4; b += SC_BLOCK) hist[b] = 0;
    __syncthreads();

    const int p0 = blockIdx.x * (SC_BLOCK * SC_PPT) + threadIdx.x;
    const unsigned r = threadIdx.x & 3;
    unsigned key[2 * SC_PPT];
    unsigned brk[2 * SC_PPT];       // slot(9b) | rank<<9  (rank < 4096)
    float    wv[SC_PPT];

#pragma unroll
    for (int k = 0; k < SC_PPT; ++k) {
        int p = p0 + k * SC_BLOCK;
        if (p < npairs) {
            int2 ij = idx[p];
            wv[k] = 0.5f / dist[p];
            unsigned s0 = (((unsigned)ij.x >> CA_BITS) << 2) + r;
            unsigned s1 = (((unsigned)ij.y >> CA_BITS) << 2) + r;
            key[2 * k]     = (unsigned)ij.y | (((unsigned)ij.x & (CHUNK - 1)) << 18);
            brk[2 * k]     = s0 | (atomicAdd(&hist[s0], 1u) << 9);
            key[2 * k + 1] = (unsigned)ij.x | (((unsigned)ij.y & (CHUNK - 1)) << 18);
            brk[2 * k + 1] = s1 | (atomicAdd(&hist[s1], 1u) << 9);
        } else {
            brk[2 * k] = brk[2 * k + 1] = 0xFFFFFFFFu;
        }
    }
    __syncthreads();
    for (int b = threadIdx.x; b < NCHUNK; b += SC_BLOCK) {
        unsigned h0 = hist[4 * b], h1 = hist[4 * b + 1], h2 = hist[4 * b + 2], h3 = hist[4 * b + 3];
        unsigned tot = h0 + h1 + h2 + h3;
        unsigned g = tot ? atomicAdd(&cursors[b], tot) : 0u;
        rbase[4 * b]     = g;
        rbase[4 * b + 1] = g + h0;
        rbase[4 * b + 2] = g + h0 + h1;
        rbase[4 * b + 3] = g + h0 + h1 + h2;
    }
    __syncthreads();

#pragma unroll
    for (int k = 0; k < SC_PPT; ++k) {
        if (brk[2 * k] != 0xFFFFFFFFu) {
            unsigned wb = __float_as_uint(wv[k]);
            entries[rbase[brk[2 * k] & 511u] + (brk[2 * k] >> 9)] =
                make_uint2(key[2 * k], wb);
            entries[rbase[brk[2 * k + 1] & 511u] + (brk[2 * k + 1] >> 9)] =
                make_uint2(key[2 * k + 1], wb);
        }
    }
}

// ---------------- Pass B: high-occupancy chunk scan ----------------
__global__ __launch_bounds__(SCAN_BLOCK) void bucket_scan2(
    const float4* __restrict__ charges, const uint2* __restrict__ entries,
    const unsigned* __restrict__ offsets, float* __restrict__ slabs,
    int natoms)
{
    __shared__ float sm[4 * CHUNK];           // channel-major: sm[ch*CHUNK + local]
    const int c = blockIdx.x / NSL;
    const int s = blockIdx.x - c * NSL;
    for (int e = threadIdx.x; e < 4 * CHUNK; e += SCAN_BLOCK) sm[e] = 0.f;
    __syncthreads();

    const unsigned beg = offsets[c];
    const unsigned cnt = offsets[c + 1] - beg;
    const unsigned e0  = beg + (unsigned)((unsigned long long)cnt * s       / NSL);
    const unsigned e1  = beg + (unsigned)((unsigned long long)cnt * (s + 1) / NSL);

    unsigned e = e0 + threadIdx.x;
    for (; e + 3u * SCAN_BLOCK < e1; e += 4u * SCAN_BLOCK) {
        uint2 en[4];
#pragma unroll
        for (int u = 0; u < 4; ++u) en[u] = entries[e + u * SCAN_BLOCK];
        float4 cq[4];
#pragma unroll
        for (int u = 0; u < 4; ++u) cq[u] = charges[en[u].x & 0x3FFFFu];
#pragma unroll
        for (int u = 0; u < 4; ++u) {
            float w = __uint_as_float(en[u].y);
            unsigned dl = en[u].x >> 18;
            atomicAdd(&sm[dl],             cq[u].x * w);
            atomicAdd(&sm[CHUNK + dl],     cq[u].y * w);
            atomicAdd(&sm[2 * CHUNK + dl], cq[u].z * w);
            atomicAdd(&sm[3 * CHUNK + dl], cq[u].w * w);
        }
    }
    for (; e < e1; e += SCAN_BLOCK) {
        uint2 en = entries[e];
        float4 cq = charges[en.x & 0x3FFFFu];
        float w = __uint_as_float(en.y);
        unsigned dl = en.x >> 18;
        atomicAdd(&sm[dl],             cq.x * w);
        atomicAdd(&sm[CHUNK + dl],     cq.y * w);
        atomicAdd(&sm[2 * CHUNK + dl], cq.z * w);
        atomicAdd(&sm[3 * CHUNK + dl], cq.w * w);
    }
    __syncthreads();

    const int c0 = c << CA_BITS;
    const int nv = min(CHUNK, natoms - c0);
    float4* dst = (float4*)(slabs + (size_t)blockIdx.x * (4 * CHUNK));
    for (int a = threadIdx.x; a < nv; a += SCAN_BLOCK)
        dst[a] = make_float4(sm[a], sm[CHUNK + a], sm[2 * CHUNK + a], sm[3 * CHUNK + a]);
}

// ---------------- reduce NSL slabs per chunk ----------------
__global__ __launch_bounds__(256) void conv_reduce(
    const float4* __restrict__ slabs, float4* __restrict__ out, int natoms)
{
    int a = blockIdx.x * 256 + threadIdx.x;
    if (a >= natoms) return;
    int c = a >> CA_BITS, l = a & (CHUNK - 1);
    const float4* p = slabs + ((size_t)(c * NSL)) * CHUNK + l;
    float4 acc = make_float4(0.f, 0.f, 0.f, 0.f);
#pragma unroll
    for (int s = 0; s < NSL; ++s) {
        float4 v = p[(size_t)s * CHUNK];
        acc.x += v.x; acc.y += v.y; acc.z += v.z; acc.w += v.w;
    }
    out[a] = acc;
}

// ---------------- fallback: direct global atomics ----------------
__global__ __launch_bounds__(256) void naive_scatter(
    const float4* __restrict__ charges, const int2* __restrict__ idx,
    const float* __restrict__ dist, float* __restrict__ out, int npairs)
{
    int t = blockIdx.x * blockDim.x + threadIdx.x;
    if (t >= npairs) return;
    int2  ij = idx[t];
    float w  = 0.5f / dist[t];
    float4 ci = charges[ij.x];
    float4 cj = charges[ij.y];
    float* oi = out + 4 * (size_t)ij.x;
    float* oj = out + 4 * (size_t)ij.y;
    atomicAdd(oi + 0, cj.x * w); atomicAdd(oi + 1, cj.y * w);
    atomicAdd(oi + 2, cj.z * w); atomicAdd(oi + 3, cj.w * w);
    atomicAdd(oj + 0, ci.x * w); atomicAdd(oj + 1, ci.y * w);
    atomicAdd(oj + 2, ci.z * w); atomicAdd(oj + 3, ci.w * w);
}

extern "C" void kernel_launch(void* const* d_in, const int* in_sizes, int n_in,
                              void* d_out, int out_size, void* d_ws, size_t ws_size,
                              hipStream_t stream) {
    const float4* charges = (const float4*)d_in[0];
    const int2*   idx     = (const int2*)  d_in[1];
    const float*  dist    = (const float*) d_in[2];
    float*        out     = (float*)d_out;

    const int natoms = in_sizes[0] / 4;     // 200000
    const int npairs = in_sizes[2];         // 8000000
    const int total  = out_size;            // 800000

    const int grid = NCHUNK * NSL;          // 980

    // ws layout: [counts@0 | offsets@1024 | cursors@2048, hdr 4096]
    //            [entries 2*npairs*8][slabs 980*32KB]
    const size_t HDR       = 4096;
    const size_t ent_bytes = ((size_t)2 * npairs * 8 + 255) & ~(size_t)255;   // 128 MB
    const size_t o_slabs   = HDR + ent_bytes;
    const size_t slab_bytes = (size_t)grid * (4 * CHUNK) * sizeof(float);     // 32.1 MB
    const size_t need      = o_slabs + slab_bytes;                            // ~160.4 MB

    if (ws_size >= need && natoms <= NCHUNK * CHUNK && natoms <= (1 << 18) && (total & 3) == 0) {
        unsigned* counts  = (unsigned*)d_ws;
        unsigned* offsets = (unsigned*)((char*)d_ws + 1024);
        unsigned* cursors = (unsigned*)((char*)d_ws + 2048);
        uint2*    entries = (uint2*)((char*)d_ws + HDR);
        float*    slabs   = (float*)((char*)d_ws + o_slabs);

        hipMemsetAsync(d_ws, 0, HDR, stream);
        bucket_count<<<1024, CT_BLOCK, 0, stream>>>((const int4*)idx, counts, npairs);
        bucket_prefix<<<1, 32, 0, stream>>>(counts, offsets, cursors);
        const int sc_grid = (npairs + SC_BLOCK * SC_PPT - 1) / (SC_BLOCK * SC_PPT);
        bucket_scatter<<<sc_grid, SC_BLOCK, 0, stream>>>(idx, dist, entries, cursors, npairs);
        bucket_scan2<<<grid, SCAN_BLOCK, 0, stream>>>(charges, entries, offsets, slabs, natoms);
        conv_reduce<<<(natoms + 255) / 256, 256, 0, stream>>>(
            (const float4*)slabs, (float4*)out, natoms);
    } else {
        hipMemsetAsync(d_out, 0, (size_t)total * sizeof(float), stream);
        naive_scatter<<<(npairs + 255) / 256, 256, 0, stream>>>(
            charges, idx, dist, out, npairs);
    }
}